// Round 7
// baseline (29.335 us; speedup 1.0000x reference)
//
#include <hip/hip_runtime.h>

#define HWX 65536
#define NQ 128      // N (queries)
#define KT 64       // K (targets)
#define CC 134      // classes
#define BB 2        // batch
#define NW 256      // k-windows
#define WIN 256     // floats per window
#define SUB 64      // floats per sub-slice (staged tile K-width)
#define NSUB 4      // sub-slices per window
#define EPSI 1e-5f

typedef __attribute__((ext_vector_type(4))) float f32x4;
typedef __attribute__((ext_vector_type(8))) short bf16x8;
typedef __attribute__((ext_vector_type(2))) unsigned int u32x2;

static __device__ __forceinline__ unsigned int cvtpk(float lo, float hi) {
  unsigned int r;
  asm("v_cvt_pk_bf16_f32 %0, %1, %2" : "=v"(r) : "v"(lo), "v"(hi));
  return r;
}

// ---------------- int64-vs-int32 detection (atomic-fallback path only) ------
__global__ void hm_detect(const unsigned int* __restrict__ t,
                          unsigned int* __restrict__ flag) {
  unsigned int w = t[threadIdx.x * 2 + 1];
  unsigned long long any = __ballot(w != 0u);
  if (threadIdx.x == 0) *flag = (any != 0ull) ? 1u : 0u;  // 1 => int32 data
}

// ---------------- stage 1: LDS-staged MFMA over one 256-wide k-window -------
// Round-3-proven structure (double-buffered LDS + __syncthreads), tile
// halved along K (SUB=64): LDS = 48 KB -> 2 blocks/CU co-resident, whose
// phase-shifted load streams cover each other's compute/barrier bubbles.
// grid = BB*NW = 512 blocks, 512 threads (8 waves).
template <bool ATOMIC>
__global__ __launch_bounds__(512, 4)
void hm_stage1(const float* __restrict__ in_mask, const float* __restrict__ tg_mask,
               float* __restrict__ Ipart, float* __restrict__ RSin,
               float* __restrict__ RStg) {
  const int w = blockIdx.x & (NW - 1);
  const int b = blockIdx.x >> 8;
  const int tid = threadIdx.x;
  const int lane = tid & 63;
  const int wv = tid >> 6;            // wave 0..7
  const int srow = tid >> 4;          // staging row group 0..31
  const int c4 = (tid & 15) * 4;      // staging float col
  const int c8b = (tid & 15) * 8;     // staging byte col (4 bf16)
  const int l16 = lane & 15;
  const int lg = lane >> 4;

  __shared__ unsigned short lA[2][128 * 64];  // 16 KB x2, XOR-swizzled bf16
  __shared__ unsigned short lB[2][64 * 64];   // 8 KB x2

  const float* Ab = in_mask + (size_t)b * NQ * HWX + (size_t)w * WIN;
  const float* Bb = tg_mask + (size_t)b * KT * HWX + (size_t)w * WIN;

  f32x4 ra4[4], rb4[2];
  f32x4 acc[4];
  #pragma unroll
  for (int i = 0; i < 4; ++i) acc[i] = f32x4{0.f, 0.f, 0.f, 0.f};
  float rsA[4] = {0.f, 0.f, 0.f, 0.f};
  float rsB[2] = {0.f, 0.f};

  // 16 lanes x 16 B = 256 B contiguous per row-group per instruction
  auto ISSUE = [&](int t) {
    const int co = t * SUB + c4;
    #pragma unroll
    for (int it = 0; it < 4; ++it)
      ra4[it] = *(const f32x4*)(Ab + (size_t)(it * 32 + srow) * HWX + co);
    #pragma unroll
    for (int it = 0; it < 2; ++it)
      rb4[it] = *(const f32x4*)(Bb + (size_t)(it * 32 + srow) * HWX + co);
  };

  auto CVTW = [&](int buf) {
    char* A8 = (char*)lA[buf];
    char* B8 = (char*)lB[buf];
    #pragma unroll
    for (int it = 0; it < 4; ++it) {
      f32x4 x = ra4[it];
      rsA[it] += (x.x + x.y) + (x.z + x.w);
      u32x2 v;
      v.x = cvtpk(x.x, x.y); v.y = cvtpk(x.z, x.w);
      const int row = it * 32 + srow;
      *(u32x2*)(A8 + ((row * 128 + c8b) ^ ((row & 7) << 4))) = v;
    }
    #pragma unroll
    for (int it = 0; it < 2; ++it) {
      f32x4 x = rb4[it];
      rsB[it] += (x.x + x.y) + (x.z + x.w);
      u32x2 v;
      v.x = cvtpk(x.x, x.y); v.y = cvtpk(x.z, x.w);
      const int row = it * 32 + srow;
      *(u32x2*)(B8 + ((row * 128 + c8b) ^ ((row & 7) << 4))) = v;
    }
  };

  auto COMP = [&](int buf) {
    const char* A8 = (const char*)lA[buf];
    const char* B8 = (const char*)lB[buf];
    const int arow = wv * 16 + l16;
    const int sw = (l16 & 7) << 4;
    #pragma unroll
    for (int s = 0; s < 2; ++s) {
      bf16x8 fa = *(const bf16x8*)(A8 + ((arow * 128 + s * 64 + lg * 16) ^ sw));
      #pragma unroll
      for (int cf = 0; cf < 4; ++cf) {
        const int brow = cf * 16 + l16;
        bf16x8 fb = *(const bf16x8*)(B8 + ((brow * 128 + s * 64 + lg * 16) ^ sw));
        acc[cf] = __builtin_amdgcn_mfma_f32_16x16x32_bf16(fa, fb, acc[cf], 0, 0, 0);
      }
    }
  };

  // ---- round-3-proven pipeline over the 4 sub-slices -----------------------
  ISSUE(0);
  CVTW(0);
  __syncthreads();
  #pragma unroll
  for (int t = 0; t < NSUB; ++t) {
    if (t + 1 < NSUB) ISSUE(t + 1);
    COMP(t & 1);
    if (t + 1 < NSUB) {
      CVTW((t + 1) & 1);
      __syncthreads();
    }
  }

  // ---- write intersections (C layout: col = lane&15, row = (lane>>4)*4+j) --
  #pragma unroll
  for (int cf = 0; cf < 4; ++cf) {
    #pragma unroll
    for (int j = 0; j < 4; ++j) {
      const int row = wv * 16 + lg * 4 + j;
      const int col = cf * 16 + l16;
      if (!ATOMIC)
        Ipart[((size_t)(b * NW + w) * NQ + row) * KT + col] = acc[cf][j];
      else
        atomicAdd(&Ipart[((size_t)b * NQ + row) * KT + col], acc[cf][j]);
    }
  }

  // ---- rowsums: reduce across the 16 threads sharing each staged row -------
  #pragma unroll
  for (int it = 0; it < 4; ++it) {
    float v = rsA[it];
    v += __shfl_xor(v, 1); v += __shfl_xor(v, 2);
    v += __shfl_xor(v, 4); v += __shfl_xor(v, 8);
    rsA[it] = v;
  }
  #pragma unroll
  for (int it = 0; it < 2; ++it) {
    float v = rsB[it];
    v += __shfl_xor(v, 1); v += __shfl_xor(v, 2);
    v += __shfl_xor(v, 4); v += __shfl_xor(v, 8);
    rsB[it] = v;
  }
  if ((tid & 15) == 0) {
    if (!ATOMIC) {
      #pragma unroll
      for (int it = 0; it < 4; ++it)
        RSin[(size_t)(b * NW + w) * NQ + it * 32 + srow] = rsA[it];
      #pragma unroll
      for (int it = 0; it < 2; ++it)
        RStg[(size_t)(b * NW + w) * KT + it * 32 + srow] = rsB[it];
    } else {
      #pragma unroll
      for (int it = 0; it < 4; ++it)
        atomicAdd(&RSin[b * NQ + it * 32 + srow], rsA[it]);
      #pragma unroll
      for (int it = 0; it < 2; ++it)
        atomicAdd(&RStg[b * KT + it * 32 + srow], rsB[it]);
    }
  }
}

// ---------------- stage 2 (partial mode): reduce + dice + class gather ------
__global__ __launch_bounds__(256)
void hm_stage2(const float* __restrict__ cprob, const void* __restrict__ tcls,
               const float* __restrict__ Ipart, const float* __restrict__ RSin,
               const float* __restrict__ RStg, float* __restrict__ out) {
  const int bn = blockIdx.x;            // b*NQ + n
  const int b = bn >> 7, n = bn & 127;
  const int k = threadIdx.x & 63;
  const int wq = threadIdx.x >> 6;      // 0..3
  float I = 0.f, ra = 0.f, rg = 0.f;
  #pragma unroll 8
  for (int ww = 0; ww < NW / 4; ++ww) {
    const int w = wq * (NW / 4) + ww;
    I  += Ipart[((size_t)(b * NW + w) * NQ + n) * KT + k];
    ra += RSin[(size_t)(b * NW + w) * NQ + n];
    rg += RStg[(size_t)(b * NW + w) * KT + k];
  }
  __shared__ float sI[4][64];
  __shared__ float sG[4][64];
  __shared__ float sR[4];
  sI[wq][k] = I;
  sG[wq][k] = rg;
  if (k == 0) sR[wq] = ra;
  __syncthreads();
  if (wq == 0) {
    I  = sI[0][k] + sI[1][k] + sI[2][k] + sI[3][k];
    rg = sG[0][k] + sG[1][k] + sG[2][k] + sG[3][k];
    ra = sR[0] + sR[1] + sR[2] + sR[3];
    const unsigned int hiw = ((const unsigned int*)tcls)[k * 2 + 1];
    const bool i32 = (__ballot(hiw != 0u) != 0ull);
    int tc = i32 ? ((const int*)tcls)[b * KT + k]
                 : (int)((const long long*)tcls)[b * KT + k];
    const float c = cprob[((size_t)b * NQ + n) * CC + tc];
    out[(size_t)bn * KT + k] = c * (2.f * I + EPSI) / (ra + rg + EPSI);
  }
}

// ---------------- stage 2 (atomic fallback mode) ----------------------------
__global__ __launch_bounds__(256)
void hm_stage2_direct(const float* __restrict__ cprob, const void* __restrict__ tcls,
                      const unsigned int* __restrict__ flag,
                      const float* __restrict__ Iacc, const float* __restrict__ RSin,
                      const float* __restrict__ RStg, float* __restrict__ out) {
  const int idx = blockIdx.x * 256 + threadIdx.x;
  const int k = idx & 63;
  const int n = (idx >> 6) & 127;
  const int b = idx >> 13;
  const float I  = Iacc[idx];
  const float ra = RSin[b * NQ + n];
  const float rg = RStg[b * KT + k];
  int tc;
  if (*flag) tc = ((const int*)tcls)[b * KT + k];
  else       tc = (int)((const long long*)tcls)[b * KT + k];
  const float c = cprob[((size_t)b * NQ + n) * CC + tc];
  out[idx] = c * (2.f * I + EPSI) / (ra + rg + EPSI);
}

__global__ void hm_zero(float* __restrict__ p, int n) {
  int i = blockIdx.x * blockDim.x + threadIdx.x;
  if (i < n) p[i] = 0.f;
}

extern "C" void kernel_launch(void* const* d_in, const int* in_sizes, int n_in,
                              void* d_out, int out_size, void* d_ws, size_t ws_size,
                              hipStream_t stream) {
  const float* cprob = (const float*)d_in[0];   // (2,128,134) f32
  const float* imask = (const float*)d_in[1];   // (2,128,65536) f32
  const float* tmask = (const float*)d_in[2];   // (2,64,65536) f32
  const void*  tcls  = d_in[3];                 // (2,64) int64 (or int32)
  float* out = (float*)d_out;                   // (2,128,64) f32

  const size_t ipart_f = (size_t)BB * NW * NQ * KT;  // 4 Mi floats (16 MB)
  const size_t rsin_f  = (size_t)BB * NW * NQ;       // 65,536
  const size_t rstg_f  = (size_t)BB * NW * KT;       // 32,768
  const size_t need    = (ipart_f + rsin_f + rstg_f) * sizeof(float);

  char* ws = (char*)d_ws;
  if (ws_size >= need) {
    float* Ipart = (float*)ws;
    float* RSin  = Ipart + ipart_f;
    float* RStg  = RSin + rsin_f;
    hm_stage1<false><<<BB * NW, 512, 0, stream>>>(imask, tmask, Ipart, RSin, RStg);
    hm_stage2<<<BB * NQ, 256, 0, stream>>>(cprob, tcls, Ipart, RSin, RStg, out);
  } else {
    // small-scratch atomic fallback (~67 KB)
    float* Iacc = (float*)ws;                     // 16384 floats
    float* RSin = Iacc + (size_t)BB * NQ * KT;    // 256
    float* RStg = RSin + BB * NQ;                 // 128
    unsigned int* flag = (unsigned int*)(RStg + BB * KT);
    const int zn = BB * NQ * KT + BB * NQ + BB * KT;
    hm_zero<<<(zn + 255) / 256, 256, 0, stream>>>(Iacc, zn);
    hm_detect<<<1, 64, 0, stream>>>((const unsigned int*)tcls, flag);
    hm_stage1<true><<<BB * NW, 512, 0, stream>>>(imask, tmask, Iacc, RSin, RStg);
    hm_stage2_direct<<<(BB * NQ * KT) / 256, 256, 0, stream>>>(cprob, tcls, flag, Iacc, RSin, RStg, out);
  }
}

// Round 9
// 27.823 us; speedup vs baseline: 1.0543x; 1.0543x over previous
//
#include <hip/hip_runtime.h>

#define HWX 65536
#define NQ 128      // N (queries)
#define KT 64       // K (targets)
#define CC 134      // classes
#define BB 2        // batch
#define NW 128      // k-windows
#define WIN 512     // floats per window
#define SUB 64      // floats per sub-slice
#define NSUB 8      // sub-slices per window
#define EPSI 1e-5f

typedef __attribute__((ext_vector_type(4))) float f32x4;
typedef __attribute__((ext_vector_type(8))) short bf16x8;

union FU { unsigned int u[4]; bf16x8 v; };

static __device__ __forceinline__ unsigned int cvtpk(float lo, float hi) {
  unsigned int r;
  asm("v_cvt_pk_bf16_f32 %0, %1, %2" : "=v"(r) : "v"(lo), "v"(hi));
  return r;
}

// async global->LDS, 16B per lane; LDS dest = wave-uniform base + lane*16
// (linear). Swizzle is folded into the per-lane GLOBAL source address (G21).
static __device__ __forceinline__ void gload16(const float* g, float* l) {
  __builtin_amdgcn_global_load_lds(
      (const __attribute__((address_space(1))) void*)g,
      (__attribute__((address_space(3))) void*)l, 16, 0, 0);
}

// Explicit stage-boundary sync: EACH wave drains its own async LDS-writing
// loads (vmcnt) BEFORE the barrier -> after the barrier all waves' staged
// data is complete and visible. Do not rely on __syncthreads() alone to
// drain vmcnt for global_load_lds (round-8 NaN: it did not on this build).
#define STAGE_SYNC()                                           \
  do {                                                         \
    asm volatile("s_waitcnt vmcnt(0)" ::: "memory");           \
    __syncthreads();                                           \
  } while (0)

// ---------------- int64-vs-int32 detection (atomic-fallback path only) ------
__global__ void hm_detect(const unsigned int* __restrict__ t,
                          unsigned int* __restrict__ flag) {
  unsigned int w = t[threadIdx.x * 2 + 1];
  unsigned long long any = __ballot(w != 0u);
  if (threadIdx.x == 0) *flag = (any != 0ull) ? 1u : 0u;  // 1 => int32 data
}

// ---------------- stage 1: global_load_lds-staged MFMA ----------------------
// grid = BB*NW = 256 blocks (1/CU), 512 threads (8 waves).
// Per sub-slice (64 floats K): stage A(128x64)+B(64x64) fp32 straight into
// double-buffered LDS via global_load_lds (1024 B linear per instruction,
// XOR-swizzle on the global source chunk index). Schedule per sub-slice:
// STAGE(t+1) -> COMP(t) (loads fly under compute) -> vmcnt(0) -> barrier.
// fp32->bf16 conversion happens during fragment assembly; rowsums are
// accumulated from the same fp32 LDS reads and shfl-reduced (R3 pattern).
template <bool ATOMIC>
__global__ __launch_bounds__(512)
void hm_stage1(const float* __restrict__ in_mask, const float* __restrict__ tg_mask,
               float* __restrict__ Ipart, float* __restrict__ RSin,
               float* __restrict__ RStg) {
  const int w = blockIdx.x & (NW - 1);
  const int b = blockIdx.x >> 7;
  const int tid = threadIdx.x;
  const int lane = tid & 63;
  const int wv = tid >> 6;            // wave 0..7
  const int l16 = lane & 15;
  const int lg = lane >> 4;

  __shared__ __align__(16) float lA[2][128 * SUB];  // 32 KB x2 fp32
  __shared__ __align__(16) float lB[2][64 * SUB];   // 16 KB x2 fp32

  const float* Ab = in_mask + (size_t)b * NQ * HWX + (size_t)w * WIN;
  const float* Bb = tg_mask + (size_t)b * KT * HWX + (size_t)w * WIN;

  f32x4 acc[4];
  #pragma unroll
  for (int i = 0; i < 4; ++i) acc[i] = f32x4{0.f, 0.f, 0.f, 0.f};
  float rsA = 0.f;   // rowsum of A row (wv*16 + l16)
  float rsB = 0.f;   // rowsum of B row (wv*16 + l16), waves 0..3 only

  // one instruction = 4 rows x 256 B = 1024 B linear LDS; the source chunk
  // index is XORed by (row&7) so the read-side XOR sees conflict-free banks.
  auto STAGE = [&](int t, int buf) {
    #pragma unroll
    for (int q = 0; q < 4; ++q) {            // A: rows [wv*16, wv*16+16)
      const int r0 = wv * 16 + q * 4;
      const int row = r0 + (lane >> 4);
      const int csrc = (lane & 15) ^ (row & 7);
      gload16(Ab + (size_t)row * HWX + t * SUB + csrc * 4, &lA[buf][r0 * SUB]);
    }
    #pragma unroll
    for (int q = 0; q < 2; ++q) {            // B: rows [wv*8, wv*8+8)
      const int r0 = wv * 8 + q * 4;
      const int row = r0 + (lane >> 4);
      const int csrc = (lane & 15) ^ (row & 7);
      gload16(Bb + (size_t)row * HWX + t * SUB + csrc * 4, &lB[buf][r0 * SUB]);
    }
  };

  auto COMP = [&](int buf) {
    const float* A32 = lA[buf];
    const float* B32 = lB[buf];
    const int xA = l16 & 7;                  // == (frag row)&7 for A and B
    const int Ra = wv * 16 + l16;
    #pragma unroll
    for (int s = 0; s < 2; ++s) {
      const int g0 = s * 8 + lg * 2;         // 16B-chunk index of k-low half
      f32x4 alo = *(const f32x4*)(A32 + Ra * SUB + ((g0 ^ xA) << 2));
      f32x4 ahi = *(const f32x4*)(A32 + Ra * SUB + (((g0 + 1) ^ xA) << 2));
      rsA += (alo.x + alo.y) + (alo.z + alo.w) + (ahi.x + ahi.y) + (ahi.z + ahi.w);
      FU fa;
      fa.u[0] = cvtpk(alo.x, alo.y); fa.u[1] = cvtpk(alo.z, alo.w);
      fa.u[2] = cvtpk(ahi.x, ahi.y); fa.u[3] = cvtpk(ahi.z, ahi.w);
      #pragma unroll
      for (int cf = 0; cf < 4; ++cf) {
        const int Rb = cf * 16 + l16;
        f32x4 blo = *(const f32x4*)(B32 + Rb * SUB + ((g0 ^ xA) << 2));
        f32x4 bhi = *(const f32x4*)(B32 + Rb * SUB + (((g0 + 1) ^ xA) << 2));
        if (cf == wv)   // wave wv owns B-rowsums for rows [wv*16, wv*16+16)
          rsB += (blo.x + blo.y) + (blo.z + blo.w) + (bhi.x + bhi.y) + (bhi.z + bhi.w);
        FU fb;
        fb.u[0] = cvtpk(blo.x, blo.y); fb.u[1] = cvtpk(blo.z, blo.w);
        fb.u[2] = cvtpk(bhi.x, bhi.y); fb.u[3] = cvtpk(bhi.z, bhi.w);
        acc[cf] = __builtin_amdgcn_mfma_f32_16x16x32_bf16(fa.v, fb.v, acc[cf], 0, 0, 0);
      }
    }
  };

  // ---- pipeline: STAGE(t+1) flies under COMP(t); drain+barrier per slice ---
  STAGE(0, 0);
  STAGE_SYNC();
  #pragma unroll
  for (int t = 0; t < NSUB; ++t) {
    if (t + 1 < NSUB) STAGE(t + 1, (t + 1) & 1);
    COMP(t & 1);
    STAGE_SYNC();
  }

  // ---- write intersections (C layout: col = cf*16+l16, row = wv*16+lg*4+j) -
  #pragma unroll
  for (int cf = 0; cf < 4; ++cf) {
    #pragma unroll
    for (int j = 0; j < 4; ++j) {
      const int row = wv * 16 + lg * 4 + j;
      const int col = cf * 16 + l16;
      if (!ATOMIC)
        Ipart[((size_t)(b * NW + w) * NQ + row) * KT + col] = acc[cf][j];
      else
        atomicAdd(&Ipart[((size_t)b * NQ + row) * KT + col], acc[cf][j]);
    }
  }

  // ---- rowsums: reduce the 4 lanes (lg) sharing each row -------------------
  rsA += __shfl_xor(rsA, 16); rsA += __shfl_xor(rsA, 32);
  rsB += __shfl_xor(rsB, 16); rsB += __shfl_xor(rsB, 32);
  if (lg == 0) {
    const int row = wv * 16 + l16;
    if (!ATOMIC) RSin[(size_t)(b * NW + w) * NQ + row] = rsA;
    else         atomicAdd(&RSin[b * NQ + row], rsA);
    if (wv < 4) {
      if (!ATOMIC) RStg[(size_t)(b * NW + w) * KT + row] = rsB;  // row < 64
      else         atomicAdd(&RStg[b * KT + row], rsB);
    }
  }
}

// ---------------- stage 2 (partial mode): reduce + dice + class gather ------
__global__ __launch_bounds__(256)
void hm_stage2(const float* __restrict__ cprob, const void* __restrict__ tcls,
               const float* __restrict__ Ipart, const float* __restrict__ RSin,
               const float* __restrict__ RStg, float* __restrict__ out) {
  const int bn = blockIdx.x;            // b*NQ + n
  const int b = bn >> 7, n = bn & 127;
  const int k = threadIdx.x & 63;
  const int wq = threadIdx.x >> 6;      // 0..3
  float I = 0.f, ra = 0.f, rg = 0.f;
  #pragma unroll 8
  for (int ww = 0; ww < NW / 4; ++ww) {
    const int w = wq * (NW / 4) + ww;
    I  += Ipart[((size_t)(b * NW + w) * NQ + n) * KT + k];
    ra += RSin[(size_t)(b * NW + w) * NQ + n];
    rg += RStg[(size_t)(b * NW + w) * KT + k];
  }
  __shared__ float sI[4][64];
  __shared__ float sG[4][64];
  __shared__ float sR[4];
  sI[wq][k] = I;
  sG[wq][k] = rg;
  if (k == 0) sR[wq] = ra;
  __syncthreads();
  if (wq == 0) {
    I  = sI[0][k] + sI[1][k] + sI[2][k] + sI[3][k];
    rg = sG[0][k] + sG[1][k] + sG[2][k] + sG[3][k];
    ra = sR[0] + sR[1] + sR[2] + sR[3];
    const unsigned int hiw = ((const unsigned int*)tcls)[k * 2 + 1];
    const bool i32 = (__ballot(hiw != 0u) != 0ull);
    int tc = i32 ? ((const int*)tcls)[b * KT + k]
                 : (int)((const long long*)tcls)[b * KT + k];
    const float c = cprob[((size_t)b * NQ + n) * CC + tc];
    out[(size_t)bn * KT + k] = c * (2.f * I + EPSI) / (ra + rg + EPSI);
  }
}

// ---------------- stage 2 (atomic fallback mode) ----------------------------
__global__ __launch_bounds__(256)
void hm_stage2_direct(const float* __restrict__ cprob, const void* __restrict__ tcls,
                      const unsigned int* __restrict__ flag,
                      const float* __restrict__ Iacc, const float* __restrict__ RSin,
                      const float* __restrict__ RStg, float* __restrict__ out) {
  const int idx = blockIdx.x * 256 + threadIdx.x;
  const int k = idx & 63;
  const int n = (idx >> 6) & 127;
  const int b = idx >> 13;
  const float I  = Iacc[idx];
  const float ra = RSin[b * NQ + n];
  const float rg = RStg[b * KT + k];
  int tc;
  if (*flag) tc = ((const int*)tcls)[b * KT + k];
  else       tc = (int)((const long long*)tcls)[b * KT + k];
  const float c = cprob[((size_t)b * NQ + n) * CC + tc];
  out[idx] = c * (2.f * I + EPSI) / (ra + rg + EPSI);
}

__global__ void hm_zero(float* __restrict__ p, int n) {
  int i = blockIdx.x * blockDim.x + threadIdx.x;
  if (i < n) p[i] = 0.f;
}

extern "C" void kernel_launch(void* const* d_in, const int* in_sizes, int n_in,
                              void* d_out, int out_size, void* d_ws, size_t ws_size,
                              hipStream_t stream) {
  const float* cprob = (const float*)d_in[0];   // (2,128,134) f32
  const float* imask = (const float*)d_in[1];   // (2,128,65536) f32
  const float* tmask = (const float*)d_in[2];   // (2,64,65536) f32
  const void*  tcls  = d_in[3];                 // (2,64) int64 (or int32)
  float* out = (float*)d_out;                   // (2,128,64) f32

  const size_t ipart_f = (size_t)BB * NW * NQ * KT;  // 2,097,152 floats (8 MB)
  const size_t rsin_f  = (size_t)BB * NW * NQ;       // 32,768
  const size_t rstg_f  = (size_t)BB * NW * KT;       // 16,384
  const size_t need    = (ipart_f + rsin_f + rstg_f) * sizeof(float);

  char* ws = (char*)d_ws;
  if (ws_size >= need) {
    float* Ipart = (float*)ws;
    float* RSin  = Ipart + ipart_f;
    float* RStg  = RSin + rsin_f;
    hm_stage1<false><<<BB * NW, 512, 0, stream>>>(imask, tmask, Ipart, RSin, RStg);
    hm_stage2<<<BB * NQ, 256, 0, stream>>>(cprob, tcls, Ipart, RSin, RStg, out);
  } else {
    // small-scratch atomic fallback (~67 KB)
    float* Iacc = (float*)ws;                     // 16384 floats
    float* RSin = Iacc + (size_t)BB * NQ * KT;    // 256
    float* RStg = RSin + BB * NQ;                 // 128
    unsigned int* flag = (unsigned int*)(RStg + BB * KT);
    const int zn = BB * NQ * KT + BB * NQ + BB * KT;
    hm_zero<<<(zn + 255) / 256, 256, 0, stream>>>(Iacc, zn);
    hm_detect<<<1, 64, 0, stream>>>((const unsigned int*)tcls, flag);
    hm_stage1<true><<<BB * NW, 512, 0, stream>>>(imask, tmask, Iacc, RSin, RStg);
    hm_stage2_direct<<<(BB * NQ * KT) / 256, 256, 0, stream>>>(cprob, tcls, flag, Iacc, RSin, RStg, out);
  }
}

// Round 10
// 26.253 us; speedup vs baseline: 1.1174x; 1.0598x over previous
//
#include <hip/hip_runtime.h>

#define HWX 65536
#define NQ 128      // N (queries)
#define KT 64       // K (targets)
#define CC 134      // classes
#define BB 2        // batch
#define NW 128      // k-windows
#define WIN 512     // floats per window
#define SUB 64      // floats per A sub-tile
#define NSUB 8      // sub-tiles per window
#define EPSI 1e-5f

typedef __attribute__((ext_vector_type(4))) float f32x4;
typedef __attribute__((ext_vector_type(8))) short bf16x8;
typedef __attribute__((ext_vector_type(2))) unsigned int u32x2;

union FU { unsigned int u[4]; bf16x8 v; };

static __device__ __forceinline__ unsigned int cvtpk(float lo, float hi) {
  unsigned int r;
  asm("v_cvt_pk_bf16_f32 %0, %1, %2" : "=v"(r) : "v"(lo), "v"(hi));
  return r;
}

// async global->LDS, 16B/lane; LDS dest = wave-uniform base + lane*16 (linear).
// Swizzle is folded into the per-lane GLOBAL source address (G21 pattern).
static __device__ __forceinline__ void gload16(const float* g, float* l) {
  __builtin_amdgcn_global_load_lds(
      (const __attribute__((address_space(1))) void*)g,
      (__attribute__((address_space(3))) void*)l, 16, 0, 0);
}

// ---------------- int64-vs-int32 detection (atomic-fallback path only) ------
__global__ void hm_detect(const unsigned int* __restrict__ t,
                          unsigned int* __restrict__ flag) {
  unsigned int w = t[threadIdx.x * 2 + 1];
  unsigned long long any = __ballot(w != 0u);
  if (threadIdx.x == 0) *flag = (any != 0ull) ? 1u : 0u;  // 1 => int32 data
}

// ---------------- stage 1: barrier-free wave-private pipeline ---------------
// grid = BB*NW = 256 blocks (1/CU, 128 KB LDS), 512 threads (8 waves).
// Phase 1 (once): stage B window (64x512) as swizzled bf16 into shared LDS;
//   exact fp32 B-rowsums during conversion; ONE vmcnt(0)+__syncthreads().
// Phase 2 (main loop, NO barriers): each wave owns A rows [wv*16,+16) with a
//   wave-private double-buffered 16x64 fp32 LDS tile filled by global_load_lds.
//   Loop: ISSUE_A(t+1) -> COMP(t) -> s_waitcnt vmcnt(0) (per-wave!) -> swap.
//   8 desynchronized waves keep the CU memory queue continuously full.
template <bool ATOMIC>
__global__ __launch_bounds__(512)
void hm_stage1(const float* __restrict__ in_mask, const float* __restrict__ tg_mask,
               float* __restrict__ Ipart, float* __restrict__ RSin,
               float* __restrict__ RStg) {
  const int w = blockIdx.x & (NW - 1);
  const int b = blockIdx.x >> 7;
  const int tid = threadIdx.x;
  const int lane = tid & 63;
  const int wv = tid >> 6;            // wave 0..7
  const int l16 = lane & 15;
  const int lg = lane >> 4;

  __shared__ __align__(16) unsigned short lB[64 * 512];   // 64 KB bf16, swizzled
  __shared__ __align__(16) float lA[8][2][16 * SUB];      // 4 KB x2 per wave

  const float* Ab = in_mask + (size_t)b * NQ * HWX + (size_t)w * WIN;
  const float* Bb = tg_mask + (size_t)b * KT * HWX + (size_t)w * WIN;

  f32x4 acc[4];
  #pragma unroll
  for (int i = 0; i < 4; ++i) acc[i] = f32x4{0.f, 0.f, 0.f, 0.f};
  float rsA = 0.f;

  // ---- wave-private A tile staging (rows wv*16 + [0,16), 64 floats K) ------
  auto ISSUE_A = [&](int t, int buf) {
    float* dst = &lA[wv][buf][0];
    #pragma unroll
    for (int q = 0; q < 4; ++q) {
      const int row = q * 4 + (lane >> 4);           // 0..15 (wave-local)
      const int csrc = (lane & 15) ^ (row & 7);      // source-side XOR swizzle
      gload16(Ab + (size_t)(wv * 16 + row) * HWX + t * SUB + csrc * 4,
              dst + q * 256);                        // 4 rows x 256 B linear
    }
  };

  // ---- phase 1: prefetch A(0), then stage B window as bf16 -----------------
  ISSUE_A(0, 0);
  {
    const int brow = tid >> 3;          // 0..63
    const int bl = tid & 7;             // 8 threads per row
    float rsB = 0.f;
    char* B8 = (char*)lB;
    #pragma unroll
    for (int j = 0; j < 16; ++j) {
      const int c = bl + j * 8;         // 16B fp32 chunk index 0..127
      f32x4 x = *(const f32x4*)(Bb + (size_t)brow * HWX + c * 4);
      rsB += (x.x + x.y) + (x.z + x.w);
      u32x2 v;
      v.x = cvtpk(x.x, x.y); v.y = cvtpk(x.z, x.w);
      const int ch16 = c >> 1, half = c & 1;        // bf16 16B-chunk 0..63
      *(u32x2*)(B8 + (size_t)brow * 1024 +
                (((ch16 ^ (brow & 7)) << 4) + half * 8)) = v;
    }
    rsB += __shfl_xor(rsB, 1); rsB += __shfl_xor(rsB, 2); rsB += __shfl_xor(rsB, 4);
    if (bl == 0) {
      if (!ATOMIC) RStg[(size_t)(b * NW + w) * KT + brow] = rsB;
      else         atomicAdd(&RStg[b * KT + brow], rsB);
    }
  }
  asm volatile("s_waitcnt vmcnt(0)" ::: "memory");  // A(0) staged (gload_lds)
  __syncthreads();                                   // B visible to all waves

  // ---- COMP: one A sub-tile vs all 64 B cols (8 MFMA), fp32->bf16 on read --
  auto COMP = [&](int t, int buf) {
    const float* A32 = &lA[wv][buf][0];
    const char* B8 = (const char*)lB;
    const int x7 = l16 & 7;
    #pragma unroll
    for (int s = 0; s < 2; ++s) {
      const int g0 = s * 8 + lg * 2;                 // A 16B-chunk index
      f32x4 alo = *(const f32x4*)(A32 + l16 * SUB + ((g0 ^ x7) << 2));
      f32x4 ahi = *(const f32x4*)(A32 + l16 * SUB + (((g0 + 1) ^ x7) << 2));
      rsA += (alo.x + alo.y) + (alo.z + alo.w) + (ahi.x + ahi.y) + (ahi.z + ahi.w);
      FU fa;
      fa.u[0] = cvtpk(alo.x, alo.y); fa.u[1] = cvtpk(alo.z, alo.w);
      fa.u[2] = cvtpk(ahi.x, ahi.y); fa.u[3] = cvtpk(ahi.z, ahi.w);
      const int c16 = t * 8 + s * 4 + lg;            // B 16B-chunk in window
      #pragma unroll
      for (int cf = 0; cf < 4; ++cf) {
        const int Rb = cf * 16 + l16;
        bf16x8 fbv = *(const bf16x8*)(B8 + (size_t)Rb * 1024 +
                                      ((c16 ^ (Rb & 7)) << 4));
        acc[cf] = __builtin_amdgcn_mfma_f32_16x16x32_bf16(fa.v, fbv, acc[cf], 0, 0, 0);
      }
    }
  };

  // ---- phase 2: barrier-free per-wave pipeline over the 8 sub-tiles --------
  #pragma unroll
  for (int t = 0; t < NSUB; ++t) {
    const int buf = t & 1;
    if (t + 1 < NSUB) ISSUE_A(t + 1, buf ^ 1);
    COMP(t, buf);
    asm volatile("s_waitcnt vmcnt(0)" ::: "memory"); // own A loads complete
    __builtin_amdgcn_sched_barrier(0);               // pin: nothing hoists above
  }

  // ---- write intersections (C layout: col = cf*16+l16, row = wv*16+lg*4+j) -
  #pragma unroll
  for (int cf = 0; cf < 4; ++cf) {
    #pragma unroll
    for (int j = 0; j < 4; ++j) {
      const int row = wv * 16 + lg * 4 + j;
      const int col = cf * 16 + l16;
      if (!ATOMIC)
        Ipart[((size_t)(b * NW + w) * NQ + row) * KT + col] = acc[cf][j];
      else
        atomicAdd(&Ipart[((size_t)b * NQ + row) * KT + col], acc[cf][j]);
    }
  }

  // ---- A rowsums: reduce the 4 lanes (lg) sharing each row -----------------
  rsA += __shfl_xor(rsA, 16); rsA += __shfl_xor(rsA, 32);
  if (lg == 0) {
    const int row = wv * 16 + l16;
    if (!ATOMIC) RSin[(size_t)(b * NW + w) * NQ + row] = rsA;
    else         atomicAdd(&RSin[b * NQ + row], rsA);
  }
}

// ---------------- stage 2 (partial mode): reduce + dice + class gather ------
__global__ __launch_bounds__(256)
void hm_stage2(const float* __restrict__ cprob, const void* __restrict__ tcls,
               const float* __restrict__ Ipart, const float* __restrict__ RSin,
               const float* __restrict__ RStg, float* __restrict__ out) {
  const int bn = blockIdx.x;            // b*NQ + n
  const int b = bn >> 7, n = bn & 127;
  const int k = threadIdx.x & 63;
  const int wq = threadIdx.x >> 6;      // 0..3
  float I = 0.f, ra = 0.f, rg = 0.f;
  #pragma unroll 8
  for (int ww = 0; ww < NW / 4; ++ww) {
    const int w = wq * (NW / 4) + ww;
    I  += Ipart[((size_t)(b * NW + w) * NQ + n) * KT + k];
    ra += RSin[(size_t)(b * NW + w) * NQ + n];
    rg += RStg[(size_t)(b * NW + w) * KT + k];
  }
  __shared__ float sI[4][64];
  __shared__ float sG[4][64];
  __shared__ float sR[4];
  sI[wq][k] = I;
  sG[wq][k] = rg;
  if (k == 0) sR[wq] = ra;
  __syncthreads();
  if (wq == 0) {
    I  = sI[0][k] + sI[1][k] + sI[2][k] + sI[3][k];
    rg = sG[0][k] + sG[1][k] + sG[2][k] + sG[3][k];
    ra = sR[0] + sR[1] + sR[2] + sR[3];
    const unsigned int hiw = ((const unsigned int*)tcls)[k * 2 + 1];
    const bool i32 = (__ballot(hiw != 0u) != 0ull);
    int tc = i32 ? ((const int*)tcls)[b * KT + k]
                 : (int)((const long long*)tcls)[b * KT + k];
    const float c = cprob[((size_t)b * NQ + n) * CC + tc];
    out[(size_t)bn * KT + k] = c * (2.f * I + EPSI) / (ra + rg + EPSI);
  }
}

// ---------------- stage 2 (atomic fallback mode) ----------------------------
__global__ __launch_bounds__(256)
void hm_stage2_direct(const float* __restrict__ cprob, const void* __restrict__ tcls,
                      const unsigned int* __restrict__ flag,
                      const float* __restrict__ Iacc, const float* __restrict__ RSin,
                      const float* __restrict__ RStg, float* __restrict__ out) {
  const int idx = blockIdx.x * 256 + threadIdx.x;
  const int k = idx & 63;
  const int n = (idx >> 6) & 127;
  const int b = idx >> 13;
  const float I  = Iacc[idx];
  const float ra = RSin[b * NQ + n];
  const float rg = RStg[b * KT + k];
  int tc;
  if (*flag) tc = ((const int*)tcls)[b * KT + k];
  else       tc = (int)((const long long*)tcls)[b * KT + k];
  const float c = cprob[((size_t)b * NQ + n) * CC + tc];
  out[idx] = c * (2.f * I + EPSI) / (ra + rg + EPSI);
}

__global__ void hm_zero(float* __restrict__ p, int n) {
  int i = blockIdx.x * blockDim.x + threadIdx.x;
  if (i < n) p[i] = 0.f;
}

extern "C" void kernel_launch(void* const* d_in, const int* in_sizes, int n_in,
                              void* d_out, int out_size, void* d_ws, size_t ws_size,
                              hipStream_t stream) {
  const float* cprob = (const float*)d_in[0];   // (2,128,134) f32
  const float* imask = (const float*)d_in[1];   // (2,128,65536) f32
  const float* tmask = (const float*)d_in[2];   // (2,64,65536) f32
  const void*  tcls  = d_in[3];                 // (2,64) int64 (or int32)
  float* out = (float*)d_out;                   // (2,128,64) f32

  const size_t ipart_f = (size_t)BB * NW * NQ * KT;  // 2,097,152 floats (8 MB)
  const size_t rsin_f  = (size_t)BB * NW * NQ;       // 32,768
  const size_t rstg_f  = (size_t)BB * NW * KT;       // 16,384
  const size_t need    = (ipart_f + rsin_f + rstg_f) * sizeof(float);

  char* ws = (char*)d_ws;
  if (ws_size >= need) {
    float* Ipart = (float*)ws;
    float* RSin  = Ipart + ipart_f;
    float* RStg  = RSin + rsin_f;
    hm_stage1<false><<<BB * NW, 512, 0, stream>>>(imask, tmask, Ipart, RSin, RStg);
    hm_stage2<<<BB * NQ, 256, 0, stream>>>(cprob, tcls, Ipart, RSin, RStg, out);
  } else {
    // small-scratch atomic fallback (~67 KB)
    float* Iacc = (float*)ws;                     // 16384 floats
    float* RSin = Iacc + (size_t)BB * NQ * KT;    // 256
    float* RStg = RSin + BB * NQ;                 // 128
    unsigned int* flag = (unsigned int*)(RStg + BB * KT);
    const int zn = BB * NQ * KT + BB * NQ + BB * KT;
    hm_zero<<<(zn + 255) / 256, 256, 0, stream>>>(Iacc, zn);
    hm_detect<<<1, 64, 0, stream>>>((const unsigned int*)tcls, flag);
    hm_stage1<true><<<BB * NW, 512, 0, stream>>>(imask, tmask, Iacc, RSin, RStg);
    hm_stage2_direct<<<(BB * NQ * KT) / 256, 256, 0, stream>>>(cprob, tcls, flag, Iacc, RSin, RStg, out);
  }
}